// Round 3
// baseline (285.948 us; speedup 1.0000x reference)
//
#include <hip/hip_runtime.h>
#include <math.h>

#define B_  8
#define T_  2048
#define D_  1024
#define E_  8
#define FF_ 4096
#define N_  64            // B*E rows through the FFN
#define BT_ (B_*T_)
#define WGS 1028          // padded wgT stride (setup staging only)

// ---------------------------------------------------------------------------
// K1: logits[bt][e] = X[bt]·Wg[:,e] + bg[e], plus dispatch-softmax denominator
//     sumexp[b][e] = sum_T exp(logit).
// Wg held in REGISTERS (128 VGPR/lane); X read direct-from-global coalesced
// (no LDS in hot loop — round 2 showed the LDS round-trip was the bound:
//  4096 ds_read_b128/CU x 12cyc = 41us). Per-token 8-value cross-lane reduce.
// ---------------------------------------------------------------------------
__global__ __launch_bounds__(256) void k_logits(
    const float* __restrict__ X, const float* __restrict__ Wg,
    const float* __restrict__ bg, float* __restrict__ logits,
    float* __restrict__ sumexp)
{
    __shared__ float wgT[E_ * WGS];   // 32.9 KB, setup only

    const int tid  = threadIdx.x;
    const int lane = tid & 63;
    const int wv   = tid >> 6;

    // stage Wg transposed (one-time)
    #pragma unroll
    for (int r = 0; r < 32; ++r) {
        int idx = r * 256 + tid;               // idx = d*8 + e
        wgT[(idx & 7) * WGS + (idx >> 3)] = Wg[idx];
    }
    __syncthreads();

    // lane-resident W fragment: w4[j][e] = Wg[256j + 4*lane .. +3][e]
    // (b128 reads, consecutive lanes consecutive 16B -> conflict-free)
    float4 w4[4][8];
    #pragma unroll
    for (int j = 0; j < 4; ++j)
        #pragma unroll
        for (int e = 0; e < 8; ++e)
            w4[j][e] = *(const float4*)&wgT[e * WGS + j * 256 + lane * 4];

    const int t0 = blockIdx.x * 64 + wv * 16;   // 16 tokens per wave
    const int b  = t0 >> 11;                    // block never straddles b
    const float bgv = bg[lane & 7];

    float se = 0.f;
    const float* xrow = &X[(size_t)t0 * D_ + lane * 4];

    float4 xc[4];
    #pragma unroll
    for (int j = 0; j < 4; ++j) xc[j] = *(const float4*)&xrow[j * 256];

    for (int t = 0; t < 16; ++t) {
        float4 xn[4];
        if (t < 15) {                            // prefetch next token (uniform branch)
            #pragma unroll
            for (int j = 0; j < 4; ++j)
                xn[j] = *(const float4*)&xrow[(size_t)(t + 1) * D_ + j * 256];
        }
        float acc[8];
        #pragma unroll
        for (int e = 0; e < 8; ++e) acc[e] = 0.f;
        #pragma unroll
        for (int j = 0; j < 4; ++j) {
            const float4 x = xc[j];
            #pragma unroll
            for (int e = 0; e < 8; ++e) {
                const float4 w = w4[j][e];
                acc[e] += x.x * w.x + x.y * w.y + x.z * w.z + x.w * w.w;
            }
        }
        #pragma unroll
        for (int j = 0; j < 4; ++j) xc[j] = xn[j];

        // octet butterfly (strides 1,2,4) on all 8 values
        #pragma unroll
        for (int e = 0; e < 8; ++e) {
            acc[e] += __shfl_xor(acc[e], 1);
            acc[e] += __shfl_xor(acc[e], 2);
            acc[e] += __shfl_xor(acc[e], 4);
        }
        // select e = lane&7 (7 cndmask)
        const float a01 = (lane & 1) ? acc[1] : acc[0];
        const float a23 = (lane & 1) ? acc[3] : acc[2];
        const float a45 = (lane & 1) ? acc[5] : acc[4];
        const float a67 = (lane & 1) ? acc[7] : acc[6];
        const float a03 = (lane & 2) ? a23 : a01;
        const float a47 = (lane & 2) ? a67 : a45;
        float v = (lane & 4) ? a47 : a03;
        // sum across octets
        v += __shfl_xor(v, 8);
        v += __shfl_xor(v, 16);
        v += __shfl_xor(v, 32);
        v += bgv;
        if (lane < 8) logits[(size_t)(t0 + t) * E_ + lane] = v;
        se += __expf(v);
    }
    if (lane < 8) atomicAdd(&sumexp[b * E_ + lane], se);
}

// ---------------------------------------------------------------------------
// K2: slots partials. part[ts][(b*8+e)*1024 + d] over 32-token slices.
//     Grid (64, 8) = 512 blocks (2/CU); unroll 8 for load MLP.
// ---------------------------------------------------------------------------
__global__ __launch_bounds__(256) void k_slots_part(
    const float* __restrict__ X, const float* __restrict__ logits,
    const float* __restrict__ sumexp, float* __restrict__ part)
{
    __shared__ float wlds[32 * 8];
    __shared__ float inv[8];

    const int tid = threadIdx.x;
    const int ts = blockIdx.x, b = blockIdx.y;
    const int t0 = ts * 32;

    if (tid < 8) inv[tid] = 1.f / sumexp[b * E_ + tid];
    __syncthreads();
    wlds[tid] = __expf(logits[(size_t)b * T_ * E_ + (size_t)t0 * E_ + tid]) * inv[tid & 7];
    __syncthreads();

    float4 acc[8];
    #pragma unroll
    for (int e = 0; e < 8; ++e) { acc[e].x = acc[e].y = acc[e].z = acc[e].w = 0.f; }

    const float* xb = &X[((size_t)b * T_ + t0) * D_ + tid * 4];
    #pragma unroll 8
    for (int t = 0; t < 32; ++t) {
        const float4 x4 = *(const float4*)&xb[(size_t)t * D_];
        const float4 wA = *(const float4*)&wlds[t * 8];
        const float4 wB = *(const float4*)&wlds[t * 8 + 4];
        const float w[8] = {wA.x, wA.y, wA.z, wA.w, wB.x, wB.y, wB.z, wB.w};
        #pragma unroll
        for (int e = 0; e < 8; ++e) {
            acc[e].x += x4.x * w[e];
            acc[e].y += x4.y * w[e];
            acc[e].z += x4.z * w[e];
            acc[e].w += x4.w * w[e];
        }
    }
    #pragma unroll
    for (int e = 0; e < 8; ++e) {
        *(float4*)&part[(size_t)ts * (N_ * D_) + (size_t)(b * E_ + e) * D_ + tid * 4] = acc[e];
    }
}

// K3: reduce 64 slot partials -> slots[64][1024]
__global__ __launch_bounds__(256) void k_reduce_slots(
    const float* __restrict__ part, float* __restrict__ slots)
{
    const int i = blockIdx.x * 256 + threadIdx.x;     // 65536
    float s = 0.f;
    #pragma unroll
    for (int p = 0; p < 64; ++p) s += part[(size_t)p * (N_ * D_) + i];
    slots[i] = s;
}

// ---------------------------------------------------------------------------
// K4/K6: k-split GEMM partial: part[kc][n][f] = sum_{k tile} A[n][k]*W[k][f].
//        A is 64 x K. Thread owns 2 f-cols x 64 rows; ktile = 32.
// ---------------------------------------------------------------------------
__global__ __launch_bounds__(256) void k_gemm_part(
    const float* __restrict__ A, const float* __restrict__ W,
    float* __restrict__ part, int K, int F)
{
    __shared__ float sT[32 * 68];                 // [kk][n], pad 68

    const int tid = threadIdx.x;
    const int f0 = blockIdx.x * 512 + tid;
    const int k0 = blockIdx.y * 32;

    #pragma unroll
    for (int r = 0; r < 8; ++r) {
        int idx = r * 256 + tid;
        int n = idx >> 5, kk = idx & 31;
        sT[kk * 68 + n] = A[(size_t)n * K + k0 + kk];
    }
    __syncthreads();

    float acc0[64], acc1[64];
    #pragma unroll
    for (int n = 0; n < 64; ++n) { acc0[n] = 0.f; acc1[n] = 0.f; }

    #pragma unroll 8
    for (int kk = 0; kk < 32; ++kk) {
        const float w0 = W[(size_t)(k0 + kk) * F + f0];
        const float w1 = W[(size_t)(k0 + kk) * F + f0 + 256];
        const float4* sp = (const float4*)&sT[kk * 68];   // broadcast reads
        #pragma unroll
        for (int j = 0; j < 16; ++j) {
            const float4 s = sp[j];
            acc0[4*j+0] += s.x * w0; acc0[4*j+1] += s.y * w0;
            acc0[4*j+2] += s.z * w0; acc0[4*j+3] += s.w * w0;
            acc1[4*j+0] += s.x * w1; acc1[4*j+1] += s.y * w1;
            acc1[4*j+2] += s.z * w1; acc1[4*j+3] += s.w * w1;
        }
    }

    const size_t base = (size_t)blockIdx.y * N_ * F;
    #pragma unroll
    for (int n = 0; n < 64; ++n) {
        part[base + (size_t)n * F + f0]       = acc0[n];
        part[base + (size_t)n * F + f0 + 256] = acc1[n];
    }
}

// K5: reduce 32 GEMM1 partials + b1, SiLU -> h[64][4096]
__global__ __launch_bounds__(256) void k_reduce_silu(
    const float* __restrict__ part, const float* __restrict__ b1,
    float* __restrict__ h)
{
    const int i = blockIdx.x * 256 + threadIdx.x;     // 262144
    float s = 0.f;
    #pragma unroll
    for (int p = 0; p < 32; ++p) s += part[(size_t)p * (N_ * FF_) + i];
    s += b1[i & (FF_ - 1)];
    h[i] = s / (1.f + __expf(-s));                    // silu
}

// K7: reduce 128 GEMM2 partials + b2 -> y[64][1024]
__global__ __launch_bounds__(256) void k_reduce_bias(
    const float* __restrict__ part, const float* __restrict__ b2,
    float* __restrict__ y)
{
    const int i = blockIdx.x * 256 + threadIdx.x;     // 65536
    float s = 0.f;
    #pragma unroll
    for (int p = 0; p < 128; ++p) s += part[(size_t)p * (N_ * D_) + i];
    y[i] = s + b2[i & (D_ - 1)];
}

// ---------------------------------------------------------------------------
// K8: out[b][t][d] = sum_e softmax_e(logits)[e] * y[b*8+e][d]
//     Grid (32 tc, 8 b); thread owns 4 consecutive d (float4 stores).
// ---------------------------------------------------------------------------
__global__ __launch_bounds__(256) void k_combine(
    const float* __restrict__ logits, const float* __restrict__ y,
    float* __restrict__ out)
{
    __shared__ float wlds[64 * 8];
    const int tid = threadIdx.x;
    const int tc = blockIdx.x, b = blockIdx.y;
    const int t0 = tc * 64;

    if (tid < 64) {
        const float* lp = &logits[((size_t)b * T_ + t0 + tid) * E_];
        float ex[8]; float s = 0.f;
        #pragma unroll
        for (int i = 0; i < 8; ++i) { ex[i] = __expf(lp[i]); s += ex[i]; }
        const float invs = 1.f / s;
        #pragma unroll
        for (int i = 0; i < 8; ++i) wlds[tid * 8 + i] = ex[i] * invs;
    }
    __syncthreads();

    float4 yv[8];
    #pragma unroll
    for (int e = 0; e < 8; ++e)
        yv[e] = *(const float4*)&y[(size_t)(b * E_ + e) * D_ + tid * 4];

    #pragma unroll 4
    for (int t = 0; t < 64; ++t) {
        const float4 wA = *(const float4*)&wlds[t * 8];       // broadcast
        const float4 wB = *(const float4*)&wlds[t * 8 + 4];
        float4 a;
        a.x = wA.x*yv[0].x + wA.y*yv[1].x + wA.z*yv[2].x + wA.w*yv[3].x
            + wB.x*yv[4].x + wB.y*yv[5].x + wB.z*yv[6].x + wB.w*yv[7].x;
        a.y = wA.x*yv[0].y + wA.y*yv[1].y + wA.z*yv[2].y + wA.w*yv[3].y
            + wB.x*yv[4].y + wB.y*yv[5].y + wB.z*yv[6].y + wB.w*yv[7].y;
        a.z = wA.x*yv[0].z + wA.y*yv[1].z + wA.z*yv[2].z + wA.w*yv[3].z
            + wB.x*yv[4].z + wB.y*yv[5].z + wB.z*yv[6].z + wB.w*yv[7].z;
        a.w = wA.x*yv[0].w + wA.y*yv[1].w + wA.z*yv[2].w + wA.w*yv[3].w
            + wB.x*yv[4].w + wB.y*yv[5].w + wB.z*yv[6].w + wB.w*yv[7].w;
        *(float4*)&out[((size_t)b * T_ + t0 + t) * D_ + tid * 4] = a;
    }
}

// ---------------------------------------------------------------------------
extern "C" void kernel_launch(void* const* d_in, const int* in_sizes, int n_in,
                              void* d_out, int out_size, void* d_ws, size_t ws_size,
                              hipStream_t stream)
{
    const float* X  = (const float*)d_in[0];
    const float* Wg = (const float*)d_in[1];
    const float* bg = (const float*)d_in[2];
    const float* W1 = (const float*)d_in[3];
    const float* b1 = (const float*)d_in[4];
    const float* W2 = (const float*)d_in[5];
    const float* b2 = (const float*)d_in[6];
    float* out = (float*)d_out;

    // ws layout (fp32), ~2.1 MB total
    float* wsf    = (float*)d_ws;
    float* logits = wsf;                        // 131072
    float* sumexp = logits + BT_ * E_;          // 64
    float* slots  = sumexp + 64;                // 65536
    float* h      = slots + N_ * D_;            // 262144
    float* y      = h + N_ * FF_;               // 65536

    // Large partial buffers live in d_out (64 MB): slots-part 16 MB,
    // gemm1 32 MB, gemm2 32 MB — each dead before k_combine overwrites out.
    float* part = out;

    hipMemsetAsync(sumexp, 0, 64 * sizeof(float), stream);

    hipLaunchKernelGGL(k_logits,       dim3(BT_ / 64), dim3(256), 0, stream,
                       X, Wg, bg, logits, sumexp);
    hipLaunchKernelGGL(k_slots_part,   dim3(64, 8),    dim3(256), 0, stream,
                       X, logits, sumexp, part);
    hipLaunchKernelGGL(k_reduce_slots, dim3(256),      dim3(256), 0, stream,
                       part, slots);
    hipLaunchKernelGGL(k_gemm_part,    dim3(FF_ / 512, 1024 / 32), dim3(256), 0, stream,
                       slots, W1, part, 1024, FF_);
    hipLaunchKernelGGL(k_reduce_silu,  dim3(N_ * FF_ / 256), dim3(256), 0, stream,
                       part, b1, h);
    hipLaunchKernelGGL(k_gemm_part,    dim3(D_ / 512, FF_ / 32), dim3(256), 0, stream,
                       h, W2, part, FF_, D_);
    hipLaunchKernelGGL(k_reduce_bias,  dim3(N_ * D_ / 256), dim3(256), 0, stream,
                       part, b2, y);
    hipLaunchKernelGGL(k_combine,      dim3(32, 8), dim3(256), 0, stream,
                       logits, y, out);
}